// Round 3
// baseline (81.658 us; speedup 1.0000x reference)
//
#include <hip/hip_runtime.h>
#include <math.h>

#define NN 256
#define EPSF 1e-7f
#define NBLOCKS 512

__device__ __forceinline__ float wave_reduce_sum(float v) {
    #pragma unroll
    for (int o = 32; o > 0; o >>= 1) v += __shfl_down(v, o, 64);
    return v;
}
__device__ __forceinline__ float wave_reduce_max(float v) {
    #pragma unroll
    for (int o = 32; o > 0; o >>= 1) v = fmaxf(v, __shfl_down(v, o, 64));
    return v;
}
__device__ __forceinline__ int swz(int j) { return j + (j >> 6); }

// Single fused kernel. 2 blocks per batch (bx>>1 = batch, bx&1 = row-half).
// 256 threads: g = t>>3 picks a 4-row group, sub = t&7 a 32-wide j slice.
// Final scalar reduction is done by the last block to finish (atomic counter),
// accumulators zero-initialized by a 16B hipMemsetAsync before launch.
__global__ __launch_bounds__(256) void cox_fused(
    const float* __restrict__ pred,
    const float* __restrict__ target,
    const int* __restrict__ valid,
    float* __restrict__ acc)   // acc[0]=total, acc[1]=nvalid, ((uint*)acc)[2]=counter
{
    __shared__ float2 s_j[NN + 4];    // {tm_j, E_j = exp(pred_j)}, swizzled
    __shared__ float  s_pred[NN];
    __shared__ float  s_red[8];

    const int bx = blockIdx.x;
    const int b = bx >> 1, half = bx & 1;
    const int t = threadIdx.x;
    const int base = b * NN;

    const float p  = pred[base + t];
    const float tg = target[base + t];
    const bool  v  = valid[base + t] != 0;
    const float tm = v ? tg : -1.0f;
    const float E  = __expf(p);       // pred ~ N(0,1): direct f32 sum is safe
    s_j[swz(t)] = make_float2(tm, E);
    s_pred[t] = p;

    const int wid = t >> 6, lane = t & 63;
    float wm = wave_reduce_max(tm);
    float wc = wave_reduce_sum(v ? 1.0f : 0.0f);
    if (lane == 0) { s_red[wid] = wm; s_red[4 + wid] = wc; }
    __syncthreads();                  // publishes s_j, s_pred, s_red
    const float bmax = fmaxf(fmaxf(s_red[0], s_red[1]), fmaxf(s_red[2], s_red[3]));
    const float vcount = s_red[4] + s_red[5] + s_red[6] + s_red[7];
    const float bmax_safe = fmaxf(bmax, 1.0f);

    const int g = t >> 3, sub = t & 7;
    const int i0 = half * 128 + g * 4;
    const int j0 = sub * 32;

    float ti[4], pi[4], Ei[4];
    #pragma unroll
    for (int r = 0; r < 4; r++) {
        float2 d = s_j[swz(i0 + r)];
        ti[r] = d.x; Ei[r] = d.y; pi[r] = s_pred[i0 + r];
    }

    // Pass B: den[r] = sum_{j: tm_j >= ti[r]} E_j  (no transcendentals)
    float den[4] = {0.f, 0.f, 0.f, 0.f};
    #pragma unroll 4
    for (int k = 0; k < 32; k++) {
        float2 d = s_j[swz(j0 + k)];
        #pragma unroll
        for (int r = 0; r < 4; r++)
            den[r] += (d.x >= ti[r]) ? d.y : 0.0f;
    }
    #pragma unroll
    for (int r = 0; r < 4; r++) {
        den[r] += __shfl_xor(den[r], 1);
        den[r] += __shfl_xor(den[r], 2);
        den[r] += __shfl_xor(den[r], 4);
    }

    float invden[4], part1[4];
    #pragma unroll
    for (int r = 0; r < 4; r++) {
        invden[r] = 1.0f / den[r];
        part1[r]  = __logf(den[r]) - pi[r];   // -log_p_elim
    }

    // Pass C: product of survivor terms; one log per row (in epilogue).
    const float c1 = 1.0f + EPSF, c2 = 2.0f * EPSF;
    float prod[4] = {1.f, 1.f, 1.f, 1.f};
    #pragma unroll 4
    for (int k = 0; k < 32; k++) {
        float2 d = s_j[swz(j0 + k)];
        #pragma unroll
        for (int r = 0; r < 4; r++) {
            float term = fmaxf(fmaf(-d.y, invden[r], c1), c2);
            prod[r] *= (d.x >= ti[r]) ? term : 1.0f;
        }
    }
    #pragma unroll
    for (int r = 0; r < 4; r++) {
        prod[r] *= __shfl_xor(prod[r], 1);
        prod[r] *= __shfl_xor(prod[r], 2);
        prod[r] *= __shfl_xor(prod[r], 4);
    }

    float rsum = 0.0f;
    #pragma unroll
    for (int r = 0; r < 4; r++) {
        float tii  = fmaxf(fmaf(-Ei[r], invden[r], c1), c2);  // divide out j==i
        float l2   = __logf(tii / prod[r]);
        float elim = ((ti[r] < bmax) && (ti[r] > 0.0f)) ? 1.0f : 0.0f;
        float w    = fminf(fmaxf((bmax - ti[r]) / bmax_safe, 0.0f), 1.0f);
        rsum += (part1[r] + l2) * elim * w;
    }
    rsum = (sub == 0) ? rsum : 0.0f;   // each row counted once across the 8 subs

    float wsum = wave_reduce_sum(rsum);
    __syncthreads();
    if (lane == 0) s_red[wid] = wsum;
    __syncthreads();

    if (t == 0) {
        float tot  = s_red[0] + s_red[1] + s_red[2] + s_red[3];
        float flag = (vcount >= 2.0f) ? 1.0f : 0.0f;
        atomicAdd(&acc[0], tot * flag);
        if (half == 0) atomicAdd(&acc[1], flag);
        __threadfence();
        unsigned* counter = (unsigned*)(acc + 2);
        unsigned old = atomicAdd(counter, 1u);
        if (old == NBLOCKS - 1) {
            // all 512 block contributions visible; device-scope coherent re-read
            float total = atomicAdd(&acc[0], 0.0f);
            float nf    = atomicAdd(&acc[1], 0.0f);
            acc[4] = total / fmaxf(nf, 1.0f);   // staging slot
        }
    }
}

// d_out may not alias ws; copy the scalar with a 1-thread kernel is overkill —
// use the same kernel? Simpler: last block writes d_out directly.
__global__ void cox_copy(const float* __restrict__ acc, float* __restrict__ out) {
    out[0] = acc[4];
}

extern "C" void kernel_launch(void* const* d_in, const int* in_sizes, int n_in,
                              void* d_out, int out_size, void* d_ws, size_t ws_size,
                              hipStream_t stream) {
    const float* pred   = (const float*)d_in[0];
    const float* target = (const float*)d_in[1];
    const int*   valid  = (const int*)d_in[2];
    float* acc = (float*)d_ws;   // [0]=total [1]=nvalid [2]=counter [4]=result
    hipMemsetAsync(d_ws, 0, 16, stream);
    cox_fused<<<NBLOCKS, 256, 0, stream>>>(pred, target, valid, acc);
    // write result to d_out: last block wrote acc[4]; copy D2D (graph-legal)
    hipMemcpyAsync(d_out, acc + 4, sizeof(float), hipMemcpyDeviceToDevice, stream);
}

// Round 4
// 64.578 us; speedup vs baseline: 1.2645x; 1.2645x over previous
//
#include <hip/hip_runtime.h>
#include <math.h>

#define NN 256
#define EPSF 1e-7f

__device__ __forceinline__ float wave_reduce_sum(float v) {
    #pragma unroll
    for (int o = 32; o > 0; o >>= 1) v += __shfl_down(v, o, 64);
    return v;
}
__device__ __forceinline__ float wave_reduce_max(float v) {
    #pragma unroll
    for (int o = 32; o > 0; o >>= 1) v = fmaxf(v, __shfl_down(v, o, 64));
    return v;
}
__device__ __forceinline__ int swz(int j) { return j + (j >> 6); }  // break stride-32-element bank alias

// 2 blocks per batch (bx>>1 = batch, bx&1 = row-half). 256 threads:
// g = t>>3 picks a 4-row group, sub = t&7 picks a 32-wide j slice.
// Each thread accumulates den (sum of E over risk set) and prod (product of
// survivor terms) for 4 rows over its j slice; shfl_xor combines the 8 subs.
__global__ __launch_bounds__(256) void cox_main(
    const float* __restrict__ pred,
    const float* __restrict__ target,
    const int* __restrict__ valid,
    float* __restrict__ ws_partial,   // [512] per-block partial (already *flag)
    float* __restrict__ ws_flag)      // [256] per-batch valid flag
{
    __shared__ float2 s_j[NN + 4];    // {tm_j, E_j = exp(pred_j)}, swizzled
    __shared__ float  s_pred[NN];
    __shared__ float  s_red[8];

    const int bx = blockIdx.x;
    const int b = bx >> 1, half = bx & 1;
    const int t = threadIdx.x;
    const int base = b * NN;

    const float p  = pred[base + t];
    const float tg = target[base + t];
    const bool  v  = valid[base + t] != 0;
    const float tm = v ? tg : -1.0f;
    const float E  = __expf(p);       // pred ~ N(0,1): no overflow, direct sum is f32-safe
    s_j[swz(t)] = make_float2(tm, E);
    s_pred[t] = p;

    const int wid = t >> 6, lane = t & 63;
    float wm = wave_reduce_max(tm);
    float wc = wave_reduce_sum(v ? 1.0f : 0.0f);
    if (lane == 0) { s_red[wid] = wm; s_red[4 + wid] = wc; }
    __syncthreads();                  // publishes s_j, s_pred, s_red
    const float bmax = fmaxf(fmaxf(s_red[0], s_red[1]), fmaxf(s_red[2], s_red[3]));
    const float vcount = s_red[4] + s_red[5] + s_red[6] + s_red[7];
    const float bmax_safe = fmaxf(bmax, 1.0f);

    const int g = t >> 3, sub = t & 7;
    const int i0 = half * 128 + g * 4;   // first of this thread's 4 rows
    const int j0 = sub * 32;             // this thread's j slice

    float ti[4], pi[4], Ei[4];
    #pragma unroll
    for (int r = 0; r < 4; r++) {
        float2 d = s_j[swz(i0 + r)];
        ti[r] = d.x; Ei[r] = d.y; pi[r] = s_pred[i0 + r];
    }

    // Pass B: den[r] = sum_{j: tm_j >= ti[r]} E_j  (no transcendentals)
    float den[4] = {0.f, 0.f, 0.f, 0.f};
    #pragma unroll 4
    for (int k = 0; k < 32; k++) {
        float2 d = s_j[swz(j0 + k)];
        #pragma unroll
        for (int r = 0; r < 4; r++)
            den[r] += (d.x >= ti[r]) ? d.y : 0.0f;
    }
    #pragma unroll
    for (int r = 0; r < 4; r++) {
        den[r] += __shfl_xor(den[r], 1);
        den[r] += __shfl_xor(den[r], 2);
        den[r] += __shfl_xor(den[r], 4);
    }

    float invden[4], part1[4];
    #pragma unroll
    for (int r = 0; r < 4; r++) {
        invden[r] = 1.0f / den[r];
        part1[r]  = __logf(den[r]) - pi[r];   // -log_p_elim = log_den - pred_i
    }

    // Pass C: prod[r] = prod_{j in risk} max(1+eps - E_j/den, 2eps); one log per row.
    const float c1 = 1.0f + EPSF, c2 = 2.0f * EPSF;
    float prod[4] = {1.f, 1.f, 1.f, 1.f};
    #pragma unroll 4
    for (int k = 0; k < 32; k++) {
        float2 d = s_j[swz(j0 + k)];
        #pragma unroll
        for (int r = 0; r < 4; r++) {
            float term = fmaxf(fmaf(-d.y, invden[r], c1), c2);
            prod[r] *= (d.x >= ti[r]) ? term : 1.0f;
        }
    }
    #pragma unroll
    for (int r = 0; r < 4; r++) {
        prod[r] *= __shfl_xor(prod[r], 1);
        prod[r] *= __shfl_xor(prod[r], 2);
        prod[r] *= __shfl_xor(prod[r], 4);
    }

    float rsum = 0.0f;
    #pragma unroll
    for (int r = 0; r < 4; r++) {
        float tii  = fmaxf(fmaf(-Ei[r], invden[r], c1), c2);   // divide out j==i term
        float l2   = __logf(tii / prod[r]);                    // = -log(prod) + log(tii)
        float elim = ((ti[r] < bmax) && (ti[r] > 0.0f)) ? 1.0f : 0.0f;
        float w    = fminf(fmaxf((bmax - ti[r]) / bmax_safe, 0.0f), 1.0f);
        rsum += (part1[r] + l2) * elim * w;
    }
    rsum = (sub == 0) ? rsum : 0.0f;   // rows counted once across the 8 subs

    float wsum = wave_reduce_sum(rsum);
    __syncthreads();
    if (lane == 0) s_red[wid] = wsum;
    __syncthreads();
    if (t == 0) {
        float tot  = s_red[0] + s_red[1] + s_red[2] + s_red[3];
        float flag = (vcount >= 2.0f) ? 1.0f : 0.0f;
        ws_partial[bx] = tot * flag;
        if (half == 0) ws_flag[b] = flag;
    }
}

__global__ __launch_bounds__(256) void cox_final(
    const float* __restrict__ ws_partial,
    const float* __restrict__ ws_flag,
    float* __restrict__ out)
{
    __shared__ float s1[4], s2[4];
    const int i = threadIdx.x;
    const int wid = i >> 6, lane = i & 63;
    float rt = wave_reduce_sum(ws_partial[i] + ws_partial[NN + i]);
    float rf = wave_reduce_sum(ws_flag[i]);
    if (lane == 0) { s1[wid] = rt; s2[wid] = rf; }
    __syncthreads();
    if (i == 0) {
        float tot = s1[0] + s1[1] + s1[2] + s1[3];
        float nf  = s2[0] + s2[1] + s2[2] + s2[3];
        out[0] = tot / fmaxf(nf, 1.0f);
    }
}

extern "C" void kernel_launch(void* const* d_in, const int* in_sizes, int n_in,
                              void* d_out, int out_size, void* d_ws, size_t ws_size,
                              hipStream_t stream) {
    const float* pred   = (const float*)d_in[0];
    const float* target = (const float*)d_in[1];
    const int*   valid  = (const int*)d_in[2];
    float* ws = (float*)d_ws;            // [0:512) block partials, [512:768) flags
    cox_main<<<512, 256, 0, stream>>>(pred, target, valid, ws, ws + 512);
    cox_final<<<1, 256, 0, stream>>>(ws, ws + 512, (float*)d_out);
}